// Round 11
// baseline (54.062 us; speedup 1.0000x reference)
//
#include <hip/hip_runtime.h>

// B=8192, D=1024, C=90, K=16.
// R11 = R9 (passing, 25 us) minus one dispatch:
//  (1) bin_labels (proven): per-class lists + counts; also zeroes the
//      int64 loss accumulator + done counter (runs every launch -> graph-safe).
//  (2) quad_fused: R9's quad_dots compute VERBATIM (wave = 4 same-class
//      samples x D-half, XCD-pinned classes, 4-k-group REDUCE16), then
//      per-wave losses quantized to fixed-point (2^-42) -> per-block int64
//      -> ONE global atomicAdd + done-counter per block; last block writes
//      the mean. Integer adds commute -> bit-deterministic output.

#define B_SAMP  8192
#define K_SUB   16
#define C_CLS   90
#define LISTCAP 192             // per-class capacity (mean 91, ~10 sigma)
#define F4_ROW  256             // float4 per D=1024 row
#define TSLOT   192             // block slots per XCD group (2 quads each)
#define NBLK    (8 * TSLOT)     // 1536
#define SCALE   4398046511104.0 // 2^42

// ws layout (bytes)
#define OFF_COUNTS 0            // 90 ints
#define OFF_LISTS  4096         // 90*192 ints
#define OFF_SUM    (2u << 20)   // u64 scaled loss sum
#define OFF_DONE   ((2u << 20) + 128)  // u32 done counter (own cache line)

template <int CTRL>
__device__ __forceinline__ float dpp_qperm(float v) {
    return __int_as_float(__builtin_amdgcn_update_dpp(
        0, __float_as_int(v), CTRL, 0xF, 0xF, true));
}

__device__ __forceinline__ float dot8(float4 q0, float4 q1, float4 y0, float4 y1)
{
    float t = 0.0f;
    t = fmaf(y0.x, q0.x, t); t = fmaf(y0.y, q0.y, t);
    t = fmaf(y0.z, q0.z, t); t = fmaf(y0.w, q0.w, t);
    t = fmaf(y1.x, q1.x, t); t = fmaf(y1.y, q1.y, t);
    t = fmaf(y1.z, q1.z, t); t = fmaf(y1.w, q1.w, t);
    return t;
}

// 16-lane-group epilogue (verified R6-R9).
__device__ __forceinline__ float sample_loss16(float r, int kk)
{
    const float d = 1.0f - r;
    float S = d;
    S += __shfl_xor(S, 1, 64);
    S += __shfl_xor(S, 2, 64);
    S += __shfl_xor(S, 4, 64);
    S += __shfl_xor(S, 8, 64);
    float dmin = d;
    dmin = fminf(dmin, __shfl_xor(dmin, 1, 64));
    dmin = fminf(dmin, __shfl_xor(dmin, 2, 64));
    dmin = fminf(dmin, __shfl_xor(dmin, 4, 64));
    dmin = fminf(dmin, __shfl_xor(dmin, 8, 64));
    int cand = (d == dmin) ? kk : 99;      // first-min == jnp.argmin
    cand = min(cand, __shfl_xor(cand, 1, 64));
    cand = min(cand, __shfl_xor(cand, 2, 64));
    cand = min(cand, __shfl_xor(cand, 4, 64));
    cand = min(cand, __shfl_xor(cand, 8, 64));
    const float inv = 1.0f / S;
    float t = (kk == cand) ? (d * d * inv)            // term1
                           : ((1.0f - d * inv) * d);  // term2
    t += __shfl_xor(t, 1, 64);
    t += __shfl_xor(t, 2, 64);
    t += __shfl_xor(t, 4, 64);
    t += __shfl_xor(t, 8, 64);
    return t;
}

// ---------------- Kernel 1: bin labels by class (90 blocks) ----------------
__global__ __launch_bounds__(256) void bin_labels(
    const int* __restrict__ labels,
    int*       __restrict__ counts,
    int*       __restrict__ lists,
    unsigned long long* __restrict__ sum_acc,
    unsigned int*       __restrict__ done_ctr)
{
    const int c    = blockIdx.x;
    const int tid  = threadIdx.x;
    const int wave = tid >> 6;
    const int lane = tid & 63;
    __shared__ int wcnt[4];

    if (c == 0 && tid == 0) { *sum_acc = 0ull; *done_ctr = 0u; }

    const int4* lv = reinterpret_cast<const int4*>(labels);

    int4 seg[8];
    int cnt = 0;
#pragma unroll
    for (int it = 0; it < 8; ++it) {
        seg[it] = lv[wave * 512 + it * 64 + lane];
        cnt += (seg[it].x == c) + (seg[it].y == c) + (seg[it].z == c) + (seg[it].w == c);
    }
#pragma unroll
    for (int off = 32; off > 0; off >>= 1) cnt += __shfl_xor(cnt, off, 64);
    if (lane == 0) wcnt[wave] = cnt;
    __syncthreads();

    int base = 0;
    for (int w = 0; w < wave; ++w) base += wcnt[w];
    const int total = wcnt[0] + wcnt[1] + wcnt[2] + wcnt[3];

#pragma unroll
    for (int it = 0; it < 8; ++it) {
        const int idx0 = (wave * 512 + it * 64 + lane) * 4;
        const int ls[4] = { seg[it].x, seg[it].y, seg[it].z, seg[it].w };
#pragma unroll
        for (int u = 0; u < 4; ++u) {
            const bool hit = (ls[u] == c);
            const unsigned long long m = __ballot(hit);
            if (hit) {
                const int p = base + (int)__popcll(m & ((1ull << lane) - 1ull));
                if (p < LISTCAP) lists[c * LISTCAP + p] = idx0 + u;
            }
            base += (int)__popcll(m);
        }
    }
    if (tid == 0) counts[c] = (total <= LISTCAP) ? total : LISTCAP;
}

// -------- Kernel 2: XCD-pinned quad dots + loss + global fixed-point sum --------
__global__ __launch_bounds__(256) void quad_fused(
    const float* __restrict__ x,
    const float* __restrict__ centers,
    const int*   __restrict__ counts,
    const int*   __restrict__ lists,
    unsigned long long* __restrict__ sum_acc,
    unsigned int*       __restrict__ done_ctr,
    float*              __restrict__ out)
{
    const int b    = blockIdx.x;
    const int g    = b & 7;                 // XCD group: classes c == g (mod 8)
    const int t    = b >> 3;
    const int tid  = threadIdx.x;
    const int wv   = tid >> 6;
    const int lane = tid & 63;
    const int pair = wv >> 1;               // 0 or 1: which quad
    const int h    = wv & 1;                // D-half

    __shared__ float sdots[4][4][16];       // [wave][sample][k]
    __shared__ float sgate[2][4];           // [pair][sample]
    __shared__ long long lsum[2];

    if (tid < 2) lsum[tid] = 0ll;

    // ---- 16-lane register scan: quad j -> (class, offset) ----
    const int cl  = g + 8 * lane;                       // lane<12 relevant
    const int n_l = (lane < 12 && cl < C_CLS) ? counts[cl] : 0;
    const int q_l = (n_l + 3) >> 2;                     // quads in this class
    int inc = q_l;
#pragma unroll
    for (int off = 1; off < 16; off <<= 1) {
        const int v = __shfl_up(inc, off, 64);
        if (lane >= off) inc += v;
    }
    const int Qg  = __shfl(inc, 15, 64);                // total quads in group
    const int exc = inc - q_l;

    const int j = 2 * t + pair;                         // this pair's quad id
    const bool blockdead = (2 * t >= Qg);               // block-uniform

    if (!blockdead) {
        const bool livepair = (j < Qg);                 // wave-uniform

        if (livepair) {
            const bool hit = (lane < 16) && (q_l > 0) && (j >= exc) && (j < inc);
            const unsigned long long m = __ballot(hit);
            const int ls   = (int)__ffsll(m) - 1;
            const int cls  = g + 8 * ls;
            const int qoff = j - __shfl(exc, ls, 64);
            const int cntc = __shfl(n_l, ls, 64);
            const int base = qoff * 4;                  // < cntc always

            const int4 grp = *reinterpret_cast<const int4*>(lists + cls * LISTCAP + base);
            int id[4];
            id[0] = grp.x;
            id[1] = (base + 1 < cntc) ? grp.y : grp.x;
            id[2] = (base + 2 < cntc) ? grp.z : grp.x;
            id[3] = (base + 3 < cntc) ? grp.w : grp.x;

            // x rows: this wave's D-half only -> x fetched exactly once per row.
            const float4* xv = reinterpret_cast<const float4*>(x);
            float4 xr[4][2];
#pragma unroll
            for (int s = 0; s < 4; ++s) {
                const size_t xo = (size_t)id[s] * F4_ROW + h * 128;
                xr[s][0] = xv[xo + lane];
                xr[s][1] = xv[xo + 64 + lane];
            }

            const float4* cb = reinterpret_cast<const float4*>(centers)
                             + (size_t)cls * (K_SUB * F4_ROW) + h * 128 + lane;

            const bool b0 = (lane & 1) != 0;
            const bool b1 = (lane & 2) != 0;
            const bool b2 = (lane & 4) != 0;
            const bool b3 = (lane & 8) != 0;
            const int kmap = 8 * (lane & 1) + 4 * ((lane >> 1) & 1)
                           + 2 * ((lane >> 2) & 1) + ((lane >> 3) & 1);

#define REDUCE16(A, OUT)                                                      \
    {                                                                         \
        _Pragma("unroll")                                                     \
        for (int jj = 0; jj < 8; ++jj) {                                      \
            const float send = b0 ? A[jj] : A[jj + 8];                        \
            const float recv = dpp_qperm<0xB1>(send);       /* xor 1 */       \
            A[jj] = (b0 ? A[jj + 8] : A[jj]) + recv;                          \
        }                                                                     \
        _Pragma("unroll")                                                     \
        for (int jj = 0; jj < 4; ++jj) {                                      \
            const float send = b1 ? A[jj] : A[jj + 4];                        \
            const float recv = dpp_qperm<0x4E>(send);       /* xor 2 */       \
            A[jj] = (b1 ? A[jj + 4] : A[jj]) + recv;                          \
        }                                                                     \
        _Pragma("unroll")                                                     \
        for (int jj = 0; jj < 2; ++jj) {                                      \
            const float send = b2 ? A[jj] : A[jj + 2];                        \
            const float recv = __shfl_xor(send, 4, 64);                       \
            A[jj] = (b2 ? A[jj + 2] : A[jj]) + recv;                          \
        }                                                                     \
        {                                                                     \
            const float send = b3 ? A[0] : A[1];                              \
            const float recv = __shfl_xor(send, 8, 64);                       \
            A[0] = (b3 ? A[1] : A[0]) + recv;                                 \
        }                                                                     \
        A[0] += __shfl_xor(A[0], 16, 64);                                     \
        A[0] += __shfl_xor(A[0], 32, 64);                                     \
        OUT = A[0];                                                           \
    }

            // 4 k-groups: only 16 accumulators live at a time (low VGPR).
#pragma unroll
            for (int kq = 0; kq < 4; ++kq) {
                float A[16];
#pragma unroll
                for (int kk = 0; kk < 4; ++kk) {
                    const int k = kq * 4 + kk;
                    const float4 q0 = cb[k * F4_ROW];
                    const float4 q1 = cb[k * F4_ROW + 64];
                    A[0 * 4 + kk] = dot8(q0, q1, xr[0][0], xr[0][1]);
                    A[1 * 4 + kk] = dot8(q0, q1, xr[1][0], xr[1][1]);
                    A[2 * 4 + kk] = dot8(q0, q1, xr[2][0], xr[2][1]);
                    A[3 * 4 + kk] = dot8(q0, q1, xr[3][0], xr[3][1]);
                }
                float r;
                REDUCE16(A, r)
                if (lane < 16) sdots[wv][kmap >> 2][kq * 4 + (kmap & 3)] = r;
            }
#undef REDUCE16

            if (h == 0 && lane < 4)
                sgate[pair][lane] = (base + lane < cntc) ? 1.0f : 0.0f;
        } else {
            // dead pair: zero its sdots half + gates, then join the barrier
            if (lane < 16) {
#pragma unroll
                for (int s = 0; s < 4; ++s) sdots[wv][s][lane] = 0.0f;
            }
            if (h == 0 && lane < 4) sgate[pair][lane] = 0.0f;
        }

        __syncthreads();

        // epilogue: wave 0 -> pair 0, wave 1 -> pair 1; quantize per wave.
        if (wv < 2) {
            const int s  = lane >> 4;
            const int kk = lane & 15;
            const float r = sdots[wv * 2][s][kk] + sdots[wv * 2 + 1][s][kk];
            float wl = sample_loss16(r, kk) * sgate[wv][s];
            wl += __shfl_xor(wl, 16, 64);
            wl += __shfl_xor(wl, 32, 64);
            if (lane == 0)
                lsum[wv] = (long long)__double2ll_rn((double)wl * SCALE);
        }
    }

    __syncthreads();

    // ---- one global int64 atomic + done counter per block ----
    if (tid == 0) {
        const long long q = lsum[0] + lsum[1];
        if (q != 0ll) atomicAdd(sum_acc, (unsigned long long)q);
        __threadfence();
        const unsigned int old = atomicAdd(done_ctr, 1u);
        if (old == (unsigned int)(NBLK - 1)) {
            const unsigned long long tot = atomicAdd(sum_acc, 0ull);
            out[0] = (float)((double)(long long)tot * (1.0 / (SCALE * (double)B_SAMP)));
        }
    }
}

extern "C" void kernel_launch(void* const* d_in, const int* in_sizes, int n_in,
                              void* d_out, int out_size, void* d_ws, size_t ws_size,
                              hipStream_t stream)
{
    const float* x       = (const float*)d_in[0];
    const int*   labels  = (const int*)  d_in[1];
    const float* centers = (const float*)d_in[2];
    float*       out     = (float*)d_out;
    char*        ws      = (char*)d_ws;

    int*                counts   = (int*)               (ws + OFF_COUNTS);
    int*                lists    = (int*)               (ws + OFF_LISTS);
    unsigned long long* sum_acc  = (unsigned long long*)(ws + OFF_SUM);
    unsigned int*       done_ctr = (unsigned int*)      (ws + OFF_DONE);

    bin_labels<<<C_CLS, 256, 0, stream>>>(labels, counts, lists, sum_acc, done_ctr);
    quad_fused<<<NBLK,  256, 0, stream>>>(x, centers, counts, lists, sum_acc, done_ctr, out);
}

// Round 12
// 26.517 us; speedup vs baseline: 2.0388x; 2.0388x over previous
//
#include <hip/hip_runtime.h>

// B=8192, D=1024, C=90, K=16.
// R12 = R9 with the hot kernel re-shaped for occupancy:
//   wave = (quad of 4 same-class samples, D-QUARTER of 256).
//   Per wave: 4 x float4-loads (16 VGPR, all in flight), per-k-group 4
//   center loads, A[16] accs, REDUCE16 (DPP+shfl), sdots write.
//   Block = ONE quad (4 waves = 4 quarters), one barrier, wave-0 epilogue.
//   ~2100 live blocks x 4 waves ~= 8 waves/SIMD at ~60 VGPR -> latency hidden.
//   Deterministic: partials + tiny reduce kernel (NO global atomics - proven
//   toxic in R6/R11).

#define B_SAMP  8192
#define K_SUB   16
#define C_CLS   90
#define LISTCAP 192             // per-class capacity (mean 91, ~10 sigma)
#define F4_ROW  256             // float4 per D=1024 row
#define TSLOT   384             // quad slots per XCD group (max ~320 @5sigma)
#define NBLK    (8 * TSLOT)     // 3072 blocks, 1 quad each
#define NPART   NBLK

// ws layout (bytes)
#define OFF_COUNTS 0            // 90 ints
#define OFF_LISTS  4096         // 90*192 ints
#define OFF_PART   (1u << 20)   // NPART floats

template <int CTRL>
__device__ __forceinline__ float dpp_qperm(float v) {
    return __int_as_float(__builtin_amdgcn_update_dpp(
        0, __float_as_int(v), CTRL, 0xF, 0xF, true));
}

// 16-lane-group epilogue (verified R6-R9).
__device__ __forceinline__ float sample_loss16(float r, int kk)
{
    const float d = 1.0f - r;
    float S = d;
    S += __shfl_xor(S, 1, 64);
    S += __shfl_xor(S, 2, 64);
    S += __shfl_xor(S, 4, 64);
    S += __shfl_xor(S, 8, 64);
    float dmin = d;
    dmin = fminf(dmin, __shfl_xor(dmin, 1, 64));
    dmin = fminf(dmin, __shfl_xor(dmin, 2, 64));
    dmin = fminf(dmin, __shfl_xor(dmin, 4, 64));
    dmin = fminf(dmin, __shfl_xor(dmin, 8, 64));
    int cand = (d == dmin) ? kk : 99;      // first-min == jnp.argmin
    cand = min(cand, __shfl_xor(cand, 1, 64));
    cand = min(cand, __shfl_xor(cand, 2, 64));
    cand = min(cand, __shfl_xor(cand, 4, 64));
    cand = min(cand, __shfl_xor(cand, 8, 64));
    const float inv = 1.0f / S;
    float t = (kk == cand) ? (d * d * inv)            // term1
                           : ((1.0f - d * inv) * d);  // term2
    t += __shfl_xor(t, 1, 64);
    t += __shfl_xor(t, 2, 64);
    t += __shfl_xor(t, 4, 64);
    t += __shfl_xor(t, 8, 64);
    return t;
}

// ---------------- Kernel 1: bin labels by class (90 blocks) ----------------
__global__ __launch_bounds__(256) void bin_labels(
    const int* __restrict__ labels,
    int*       __restrict__ counts,
    int*       __restrict__ lists)
{
    const int c    = blockIdx.x;
    const int tid  = threadIdx.x;
    const int wave = tid >> 6;
    const int lane = tid & 63;
    __shared__ int wcnt[4];

    const int4* lv = reinterpret_cast<const int4*>(labels);

    int4 seg[8];
    int cnt = 0;
#pragma unroll
    for (int it = 0; it < 8; ++it) {
        seg[it] = lv[wave * 512 + it * 64 + lane];
        cnt += (seg[it].x == c) + (seg[it].y == c) + (seg[it].z == c) + (seg[it].w == c);
    }
#pragma unroll
    for (int off = 32; off > 0; off >>= 1) cnt += __shfl_xor(cnt, off, 64);
    if (lane == 0) wcnt[wave] = cnt;
    __syncthreads();

    int base = 0;
    for (int w = 0; w < wave; ++w) base += wcnt[w];
    const int total = wcnt[0] + wcnt[1] + wcnt[2] + wcnt[3];

#pragma unroll
    for (int it = 0; it < 8; ++it) {
        const int idx0 = (wave * 512 + it * 64 + lane) * 4;
        const int ls[4] = { seg[it].x, seg[it].y, seg[it].z, seg[it].w };
#pragma unroll
        for (int u = 0; u < 4; ++u) {
            const bool hit = (ls[u] == c);
            const unsigned long long m = __ballot(hit);
            if (hit) {
                const int p = base + (int)__popcll(m & ((1ull << lane) - 1ull));
                if (p < LISTCAP) lists[c * LISTCAP + p] = idx0 + u;
            }
            base += (int)__popcll(m);
        }
    }
    if (tid == 0) counts[c] = (total <= LISTCAP) ? total : LISTCAP;
}

// -------- Kernel 2: block = quad; wave = D-quarter of that quad --------
__global__ __launch_bounds__(256) void quad_dots4(
    const float* __restrict__ x,
    const float* __restrict__ centers,
    const int*   __restrict__ counts,
    const int*   __restrict__ lists,
    float*       __restrict__ partials)
{
    const int b    = blockIdx.x;
    const int g    = b & 7;                 // XCD group: classes c == g (mod 8)
    const int t    = b >> 3;                // quad slot within group
    const int tid  = threadIdx.x;
    const int wv   = tid >> 6;              // D-quarter index 0..3
    const int lane = tid & 63;

    __shared__ float sdots[4][4][16];       // [quarter][sample][k]

    // ---- 16-lane register scan: quad t -> (class, offset) ----
    const int cl  = g + 8 * lane;                       // lane<12 relevant
    const int n_l = (lane < 12 && cl < C_CLS) ? counts[cl] : 0;
    const int q_l = (n_l + 3) >> 2;                     // quads in this class
    int inc = q_l;
#pragma unroll
    for (int off = 1; off < 16; off <<= 1) {
        const int v = __shfl_up(inc, off, 64);
        if (lane >= off) inc += v;
    }
    const int Qg  = __shfl(inc, 15, 64);                // total quads in group
    const int exc = inc - q_l;

    if (t >= Qg) {                                      // dead block (uniform)
        if (tid == 0) partials[b] = 0.0f;
        return;
    }

    const bool hit = (lane < 16) && (q_l > 0) && (t >= exc) && (t < inc);
    const unsigned long long m = __ballot(hit);
    const int ls   = (int)__ffsll(m) - 1;
    const int cls  = g + 8 * ls;
    const int qoff = t - __shfl(exc, ls, 64);
    const int cntc = __shfl(n_l, ls, 64);
    const int base = qoff * 4;                          // < cntc always

    const int4 grp = *reinterpret_cast<const int4*>(lists + cls * LISTCAP + base);
    int id[4];
    id[0] = grp.x;
    id[1] = (base + 1 < cntc) ? grp.y : grp.x;
    id[2] = (base + 2 < cntc) ? grp.z : grp.x;
    id[3] = (base + 3 < cntc) ? grp.w : grp.x;

    // ---- x: this wave's D-quarter of the 4 rows (4 loads, all in flight) ----
    const float4* xv = reinterpret_cast<const float4*>(x) + (wv * 64 + lane);
    float4 xr[4];
#pragma unroll
    for (int s = 0; s < 4; ++s)
        xr[s] = xv[(size_t)id[s] * F4_ROW];

    const float4* cb = reinterpret_cast<const float4*>(centers)
                     + ((size_t)cls * K_SUB * F4_ROW + wv * 64 + lane);

    const bool b0 = (lane & 1) != 0;
    const bool b1 = (lane & 2) != 0;
    const bool b2 = (lane & 4) != 0;
    const bool b3 = (lane & 8) != 0;
    const int kmap = 8 * (lane & 1) + 4 * ((lane >> 1) & 1)
                   + 2 * ((lane >> 2) & 1) + ((lane >> 3) & 1);

#define REDUCE16(A, OUT)                                                      \
    {                                                                         \
        _Pragma("unroll")                                                     \
        for (int jj = 0; jj < 8; ++jj) {                                      \
            const float send = b0 ? A[jj] : A[jj + 8];                        \
            const float recv = dpp_qperm<0xB1>(send);       /* xor 1 */       \
            A[jj] = (b0 ? A[jj + 8] : A[jj]) + recv;                          \
        }                                                                     \
        _Pragma("unroll")                                                     \
        for (int jj = 0; jj < 4; ++jj) {                                      \
            const float send = b1 ? A[jj] : A[jj + 4];                        \
            const float recv = dpp_qperm<0x4E>(send);       /* xor 2 */       \
            A[jj] = (b1 ? A[jj + 4] : A[jj]) + recv;                          \
        }                                                                     \
        _Pragma("unroll")                                                     \
        for (int jj = 0; jj < 2; ++jj) {                                      \
            const float send = b2 ? A[jj] : A[jj + 2];                        \
            const float recv = __shfl_xor(send, 4, 64);                       \
            A[jj] = (b2 ? A[jj + 2] : A[jj]) + recv;                          \
        }                                                                     \
        {                                                                     \
            const float send = b3 ? A[0] : A[1];                              \
            const float recv = __shfl_xor(send, 8, 64);                       \
            A[0] = (b3 ? A[1] : A[0]) + recv;                                 \
        }                                                                     \
        A[0] += __shfl_xor(A[0], 16, 64);                                     \
        A[0] += __shfl_xor(A[0], 32, 64);                                     \
        OUT = A[0];                                                           \
    }

    // ---- 4 k-groups: 4 center loads in flight, 16 accs live ----
#pragma unroll
    for (int kq = 0; kq < 4; ++kq) {
        float4 q[4];
#pragma unroll
        for (int kk = 0; kk < 4; ++kk)
            q[kk] = cb[(kq * 4 + kk) * F4_ROW];

        float A[16];
#pragma unroll
        for (int kk = 0; kk < 4; ++kk) {
#pragma unroll
            for (int s = 0; s < 4; ++s) {
                float v = xr[s].x * q[kk].x;
                v = fmaf(xr[s].y, q[kk].y, v);
                v = fmaf(xr[s].z, q[kk].z, v);
                v = fmaf(xr[s].w, q[kk].w, v);
                A[s * 4 + kk] = v;
            }
        }
        float r;
        REDUCE16(A, r)
        // A[v], v = s*4+kk -> lane holds v = kmap
        if (lane < 16) sdots[wv][kmap >> 2][kq * 4 + (kmap & 3)] = r;
    }
#undef REDUCE16

    __syncthreads();

    // ---- wave-0 epilogue: 4 samples x 16 k across 64 lanes ----
    if (wv == 0) {
        const int s  = lane >> 4;
        const int kk = lane & 15;
        const float r = sdots[0][s][kk] + sdots[1][s][kk]
                      + sdots[2][s][kk] + sdots[3][s][kk];
        const float gate = (base + s < cntc) ? 1.0f : 0.0f;
        float wl = sample_loss16(r, kk) * gate;
        wl += __shfl_xor(wl, 16, 64);
        wl += __shfl_xor(wl, 32, 64);
        if (lane == 0) partials[b] = wl;
    }
}

// ---------------- Kernel 3: final mean over NPART partials ----------------
__global__ __launch_bounds__(256) void reduce_final(
    const float* __restrict__ partials,
    float*       __restrict__ out)
{
    const int tid  = threadIdx.x;
    const int wave = tid >> 6;
    const int lane = tid & 63;
    float s = 0.0f;
    for (int i = tid; i < NPART; i += 256) s += partials[i];
#pragma unroll
    for (int off = 32; off > 0; off >>= 1) s += __shfl_xor(s, off, 64);
    __shared__ float w[4];
    if (lane == 0) w[wave] = s;
    __syncthreads();
    if (tid == 0)
        out[0] = (w[0] + w[1] + w[2] + w[3]) * (1.0f / (float)B_SAMP);
}

extern "C" void kernel_launch(void* const* d_in, const int* in_sizes, int n_in,
                              void* d_out, int out_size, void* d_ws, size_t ws_size,
                              hipStream_t stream)
{
    const float* x       = (const float*)d_in[0];
    const int*   labels  = (const int*)  d_in[1];
    const float* centers = (const float*)d_in[2];
    float*       out     = (float*)d_out;
    char*        ws      = (char*)d_ws;

    int*   counts = (int*)  (ws + OFF_COUNTS);
    int*   lists  = (int*)  (ws + OFF_LISTS);
    float* parts  = (float*)(ws + OFF_PART);

    bin_labels  <<<C_CLS, 256, 0, stream>>>(labels, counts, lists);
    quad_dots4  <<<NBLK,  256, 0, stream>>>(x, centers, counts, lists, parts);
    reduce_final<<<1,     256, 0, stream>>>(parts, out);
}